// Round 6
// baseline (120.190 us; speedup 1.0000x reference)
//
#include <hip/hip_runtime.h>
#include <math.h>

#define N1 8192
#define N2 8192
#define NBATCH 2
#define KNN 16
#define NBUCKET 512
#define BWF 0.015625f      // bucket width = 8/512
#define XMINF (-4.0f)
#define NCHUNKS 128        // N1/64

typedef unsigned int uint;
typedef unsigned long long ull;

// ---------- prep: histogram of candidate x-buckets ----------
__global__ __launch_bounds__(256) void pw3_prep(
    const float* __restrict__ xyz1, const float* __restrict__ flow1,
    uint* __restrict__ hist) {
  int i = blockIdx.x * 256 + threadIdx.x;   // 0 .. B*N1-1 (exact grid)
  int b = i >> 13, m = i & (N1 - 1);
  float px = xyz1[b * 3 * N1 + m] + flow1[b * 3 * N1 + m];
  int bk = (int)floorf((px - XMINF) * (1.0f / BWF));
  bk = min(max(bk, 0), NBUCKET - 1);
  atomicAdd(&hist[(b << 9) + bk], 1u);
}

// ---------- scan: exclusive prefix per 512-bucket segment ----------
__global__ __launch_bounds__(1024) void pw3_scan(
    const uint* __restrict__ hist, uint* __restrict__ offs,
    uint* __restrict__ cur) {
  __shared__ uint buf[1024];
  int t = threadIdx.x;
  int i = t & (NBUCKET - 1);
  uint h = hist[t];
  buf[t] = h;
  __syncthreads();
  for (int off = 1; off < NBUCKET; off <<= 1) {
    uint a = (i >= off) ? buf[t - off] : 0u;
    __syncthreads();
    buf[t] += a;
    __syncthreads();
  }
  uint ex = buf[t] - h;
  offs[t] = ex;
  cur[t] = ex;
}

// ---------- scatter: sorted candidates + per-chunk bucket range ----------
__global__ __launch_bounds__(256) void pw3_scatter(
    const float* __restrict__ xyz1, const float* __restrict__ flow1,
    uint* __restrict__ cur, float4* __restrict__ sp4,
    uint* __restrict__ minb, uint* __restrict__ maxb) {
  int i = blockIdx.x * 256 + threadIdx.x;
  int b = i >> 13, m = i & (N1 - 1);
  const float* x1 = xyz1 + b * 3 * N1;
  const float* f1 = flow1 + b * 3 * N1;
  float px = x1[m] + f1[m];
  float py = x1[N1 + m] + f1[N1 + m];
  float pz = x1[2 * N1 + m] + f1[2 * N1 + m];
  int bk = (int)floorf((px - XMINF) * (1.0f / BWF));
  bk = min(max(bk, 0), NBUCKET - 1);
  uint pos = atomicAdd(&cur[(b << 9) + bk], 1u);
  float4 v;
  v.x = px; v.y = py; v.z = pz; v.w = __int_as_float(m);
  sp4[(b << 13) + pos] = v;
  int c = (int)(pos >> 6);
  atomicMin(&minb[(b << 7) + c], (uint)bk);
  atomicMax(&maxb[(b << 7) + c], (uint)bk);
}

// ---------- cross-lane helpers ----------
__device__ __forceinline__ float dpp_up1_f(float x, float old_v) {
  int r = __builtin_amdgcn_update_dpp(
      __builtin_bit_cast(int, old_v), __builtin_bit_cast(int, x),
      0x111, 0xf, 0xf, false);
  return __builtin_bit_cast(float, r);
}
__device__ __forceinline__ int dpp_up1_i(int x) {
  return __builtin_amdgcn_update_dpp(0, x, 0x111, 0xf, 0xf, false);
}
template <int J>
__device__ __forceinline__ int lx_i(int x) {
  if constexpr (J == 1)
    return __builtin_amdgcn_update_dpp(x, x, 0xB1, 0xf, 0xf, false);
  else if constexpr (J == 2)
    return __builtin_amdgcn_update_dpp(x, x, 0x4E, 0xf, 0xf, false);
  else if constexpr (J == 32)
    return __shfl_xor(x, 32);
  else
    return __builtin_amdgcn_ds_swizzle(x, (J << 10) | 0x1F);
}
template <int J>
__device__ __forceinline__ float lx_f(float x) {
  return __builtin_bit_cast(float, lx_i<J>(__builtin_bit_cast(int, x)));
}

// ---------- knn: one wave per query, frontier traversal over sorted chunks ----------
__global__ __launch_bounds__(256) void pw3_knn(
    const float* __restrict__ xyz2, const float4* __restrict__ sp4,
    const float* __restrict__ flow1, const uint* __restrict__ offs,
    const uint* __restrict__ minb, const uint* __restrict__ maxb,
    float* __restrict__ out) {
  int lane = threadIdx.x & 63;
  int sub = lane & 15;
  int wid = (int)((blockIdx.x * 256 + threadIdx.x) >> 6);  // query id
  int b = wid >> 13;
  int n = wid & (N2 - 1);

  const float* x2 = xyz2 + b * 3 * N2;
  float qx = x2[n], qy = x2[N2 + n], qz = x2[2 * N2 + n];
  float n2 = (qx * qx + qy * qy) + qz * qz;

  const float4* __restrict__ src = sp4 + ((size_t)b << 13);

  // per-lane copy of chunk bucket-range tables (chunks lane, lane+64)
  int mb0 = (int)minb[(b << 7) + lane];
  int mb1 = (int)minb[(b << 7) + 64 + lane];
  int xb0 = (int)maxb[(b << 7) + lane];
  int xb1 = (int)maxb[(b << 7) + 64 + lane];

  // ---- seed: chunk containing the query's bucket; full-wave sort-64 ----
  int bq = min(max((int)floorf((qx - XMINF) * (1.0f / BWF)), 0), NBUCKET - 1);
  uint off0 = offs[(b << 9) + bq];
  int cs = min((int)(off0 >> 6), NCHUNKS - 1);

  float4 s = src[cs * 64 + lane];
  float dv;
  int iv = __float_as_int(s.w);
  {
    float nn = fmaf(s.z, s.z, fmaf(s.y, s.y, s.x * s.x));
    float dot = fmaf(s.z, qz, fmaf(s.y, qy, s.x * qx));
    dv = (n2 - 2.0f * dot) + nn;
  }
  // bitonic sort-64 ascending on (dv, iv) lexicographic
#define CE64(K, Jv)                                                  \
  {                                                                  \
    float pd = lx_f<Jv>(dv);                                         \
    int pi = lx_i<Jv>(iv);                                           \
    bool ms = (dv < pd) || ((dv == pd) && (iv < pi));                \
    bool km = ((lane & (K)) == 0) == ((lane & (Jv)) == 0);           \
    bool tm = (ms == km);                                            \
    dv = tm ? dv : pd;                                               \
    iv = tm ? iv : pi;                                               \
  }
  CE64(2, 1)
  CE64(4, 2) CE64(4, 1)
  CE64(8, 4) CE64(8, 2) CE64(8, 1)
  CE64(16, 8) CE64(16, 4) CE64(16, 2) CE64(16, 1)
  CE64(32, 16) CE64(32, 8) CE64(32, 4) CE64(32, 2) CE64(32, 1)
  CE64(64, 32) CE64(64, 16) CE64(64, 8) CE64(64, 4) CE64(64, 2) CE64(64, 1)
#undef CE64

  // broadcast lanes 0..15 (top-16 ascending) to all four 16-lane groups
  float val = __shfl(dv, sub);
  int vidx = __shfl(iv, sub);
  float kth = __builtin_bit_cast(
      float, __builtin_amdgcn_readlane(__builtin_bit_cast(int, val), 15));

  const float NEG_INF = -INFINITY, INF = INFINITY;
  int lc = cs - 1, rc = cs + 1;

  auto rd128 = [&](int r0, int r1, int c) -> int {
    int a = __builtin_amdgcn_readlane(r0, c & 63);
    int bb = __builtin_amdgcn_readlane(r1, c & 63);
    return (c & 64) ? bb : a;
  };
  // pick nearest frontier chunk whose x-gap lower bound passes kth; -1 = stop.
  auto decide = [&]() -> int {
    float lg = INF, rg = INF;
    if (lc >= 0) {
      int mv = rd128(xb0, xb1, lc);
      float hi = (mv >= NBUCKET - 1) ? INF : (XMINF + (mv + 1) * BWF);
      lg = fmaxf(qx - hi, 0.0f);
    }
    if (rc <= NCHUNKS - 1) {
      int mv = rd128(mb0, mb1, rc);
      float lo = (mv <= 0) ? -INF : (XMINF + mv * BWF);
      rg = fmaxf(lo - qx, 0.0f);
    }
    bool left = lg <= rg;
    float g = left ? lg : rg;
    if (!(g * g <= kth)) return -1;   // INF gap also stops here
    int c = left ? lc : rc;
    if (left) --lc; else ++rc;
    return c;
  };

  int c0 = decide();
  float4 s0v;
  if (c0 >= 0) s0v = src[c0 * 64 + lane];
  while (c0 >= 0) {
    int c1 = decide();                 // stale-kth: may over-continue 1 chunk (safe)
    float4 s1v;
    if (c1 >= 0) s1v = src[c1 * 64 + lane];   // prefetch next chunk

    int civ = __float_as_int(s0v.w);
    float nn = fmaf(s0v.z, s0v.z, fmaf(s0v.y, s0v.y, s0v.x * s0v.x));
    float dot = fmaf(s0v.z, qz, fmaf(s0v.y, qy, s0v.x * qx));
    float d = (n2 - 2.0f * dot) + nn;

    ull bal = __ballot(d < kth);
    if (bal) {
      int dbits = __builtin_bit_cast(int, d);
      do {
        int l = __ffsll(bal) - 1;
        bal &= bal - 1;
        float cd = __builtin_bit_cast(
            float, __builtin_amdgcn_readlane(dbits, l));
        int ci = __builtin_amdgcn_readlane(civ, l);
        float pv = dpp_up1_f(val, NEG_INF);
        int pi = dpp_up1_i(vidx);
        bool lt = cd < val;
        bool ltp = cd < pv;
        val = lt ? (ltp ? pv : cd) : val;
        vidx = lt ? (ltp ? pi : ci) : vidx;
      } while (bal);
      kth = __builtin_bit_cast(
          float, __builtin_amdgcn_readlane(__builtin_bit_cast(int, val), 15));
    }
    c0 = c1;
    s0v = s1v;
  }

  // gather selected flows directly from flow1 (original index order)
  const float* f1 = flow1 + b * 3 * N1;
  float fx = f1[vidx], fy = f1[N1 + vidx], fz = f1[2 * N1 + vidx];
  #pragma unroll
  for (int o = 8; o > 0; o >>= 1) {
    fx += __shfl_xor(fx, o);
    fy += __shfl_xor(fy, o);
    fz += __shfl_xor(fz, o);
  }

  if (lane == 0) {
    float* op = out + b * 3 * N2;
    const float inv_k = 1.0f / KNN;
    op[n]          = qx - fx * inv_k;
    op[N2 + n]     = qy - fy * inv_k;
    op[2 * N2 + n] = qz - fz * inv_k;
  }
}

extern "C" void kernel_launch(void* const* d_in, const int* in_sizes, int n_in,
                              void* d_out, int out_size, void* d_ws, size_t ws_size,
                              hipStream_t stream) {
  const float* xyz1  = (const float*)d_in[0];
  const float* xyz2  = (const float*)d_in[1];
  const float* flow1 = (const float*)d_in[2];
  float* out = (float*)d_out;

  char* w = (char*)d_ws;
  float4* sp4 = (float4*)w;            w += (size_t)NBATCH * N1 * sizeof(float4);   // 256 KB
  uint* offs  = (uint*)w;              w += NBATCH * NBUCKET * sizeof(uint);        // 4 KB
  uint* cur   = (uint*)w;              w += NBATCH * NBUCKET * sizeof(uint);        // 4 KB
  uint* minb  = (uint*)w;              w += NBATCH * NCHUNKS * sizeof(uint);        // 1 KB
  uint* hist  = (uint*)w;              w += NBATCH * NBUCKET * sizeof(uint);        // 4 KB
  uint* maxb  = (uint*)w;              w += NBATCH * NCHUNKS * sizeof(uint);        // 1 KB

  hipMemsetAsync(minb, 0xFF, NBATCH * NCHUNKS * sizeof(uint), stream);
  hipMemsetAsync(hist, 0,
                 NBATCH * NBUCKET * sizeof(uint) + NBATCH * NCHUNKS * sizeof(uint),
                 stream);  // hist + maxb contiguous

  pw3_prep<<<(NBATCH * N1) / 256, 256, 0, stream>>>(xyz1, flow1, hist);
  pw3_scan<<<1, 1024, 0, stream>>>(hist, offs, cur);
  pw3_scatter<<<(NBATCH * N1) / 256, 256, 0, stream>>>(xyz1, flow1, cur, sp4,
                                                       minb, maxb);
  pw3_knn<<<(NBATCH * N2 * 64) / 256, 256, 0, stream>>>(xyz2, sp4, flow1, offs,
                                                        minb, maxb, out);
}

// Round 7
// 97.540 us; speedup vs baseline: 1.2322x; 1.2322x over previous
//
#include <hip/hip_runtime.h>
#include <math.h>

#define N1 8192
#define N2 8192
#define NBATCH 2
#define KNN 16
#define NBUCKET 512
#define BWF 0.015625f      // bucket width = 8/512 (exact power of two)
#define XMINF (-4.0f)
#define NCHUNKS 128        // N1/64
#define SER_MAX 12

typedef unsigned int uint;
typedef unsigned long long ull;

// ---------- fused build: LDS histogram + scan + scatter + chunk x-bounds ----------
__global__ __launch_bounds__(1024) void pw3_build(
    const float* __restrict__ xyz1, const float* __restrict__ flow1,
    float4* __restrict__ sp4, uint* __restrict__ offs,
    float* __restrict__ lox, float* __restrict__ hix) {
  __shared__ uint hist[NBUCKET];   // counts, then reused as scatter cursors
  __shared__ uint scn[NBUCKET];
  __shared__ uint cmin[NCHUNKS];
  __shared__ uint cmax[NCHUNKS];
  int b = blockIdx.x;
  int t = threadIdx.x;
  if (t < NBUCKET) hist[t] = 0u;
  if (t < NCHUNKS) { cmin[t] = 0xFFFFFFFFu; cmax[t] = 0u; }
  __syncthreads();
  const float* x1 = xyz1 + b * 3 * N1;
  const float* f1 = flow1 + b * 3 * N1;
  float px[8], py[8], pz[8];
  int bk[8];
  #pragma unroll
  for (int r = 0; r < 8; ++r) {
    int m = r * 1024 + t;
    px[r] = x1[m] + f1[m];
    py[r] = x1[N1 + m] + f1[N1 + m];
    pz[r] = x1[2 * N1 + m] + f1[2 * N1 + m];
    int bb = (int)floorf((px[r] - XMINF) * (1.0f / BWF));
    bk[r] = min(max(bb, 0), NBUCKET - 1);
    atomicAdd(&hist[bk[r]], 1u);
  }
  __syncthreads();
  uint h = 0;
  if (t < NBUCKET) { h = hist[t]; scn[t] = h; }
  __syncthreads();
  for (int off = 1; off < NBUCKET; off <<= 1) {
    uint v = 0;
    if (t < NBUCKET && t >= off) v = scn[t - off];
    __syncthreads();
    if (t < NBUCKET) scn[t] += v;
    __syncthreads();
  }
  if (t < NBUCKET) {
    uint ex = scn[t] - h;          // exclusive prefix
    offs[(b << 9) + t] = ex;
    hist[t] = ex;                  // reuse as cursor
  }
  __syncthreads();
  #pragma unroll
  for (int r = 0; r < 8; ++r) {
    int m = r * 1024 + t;
    uint pos = atomicAdd(&hist[bk[r]], 1u);
    float4 v;
    v.x = px[r]; v.y = py[r]; v.z = pz[r]; v.w = __int_as_float(m);
    sp4[(b << 13) + pos] = v;
    int c = (int)(pos >> 6);
    atomicMin(&cmin[c], (uint)bk[r]);
    atomicMax(&cmax[c], (uint)bk[r]);
  }
  __syncthreads();
  if (t < NCHUNKS) {
    float lo = (cmin[t] == 0u) ? -INFINITY : (XMINF + (float)cmin[t] * BWF);
    float hi = (cmax[t] >= (uint)(NBUCKET - 1)) ? INFINITY
                                                : (XMINF + (float)(cmax[t] + 1u) * BWF);
    lox[(b << 7) + t] = lo;
    hix[(b << 7) + t] = hi;
  }
}

// ---------- cross-lane helpers ----------
__device__ __forceinline__ float dpp_up1_f(float x, float old_v) {
  int r = __builtin_amdgcn_update_dpp(
      __builtin_bit_cast(int, old_v), __builtin_bit_cast(int, x),
      0x111, 0xf, 0xf, false);
  return __builtin_bit_cast(float, r);
}
__device__ __forceinline__ int dpp_up1_i(int x) {
  return __builtin_amdgcn_update_dpp(0, x, 0x111, 0xf, 0xf, false);
}
template <int J>
__device__ __forceinline__ int lx_i(int x) {
  if constexpr (J == 1)
    return __builtin_amdgcn_update_dpp(x, x, 0xB1, 0xf, 0xf, false);  // [1,0,3,2]
  else if constexpr (J == 2)
    return __builtin_amdgcn_update_dpp(x, x, 0x4E, 0xf, 0xf, false);  // [2,3,0,1]
  else if constexpr (J <= 31)
    return __builtin_amdgcn_ds_swizzle(x, (J << 10) | 0x1F);          // xor within 32
  else
    return __shfl_xor(x, J);                                          // 64-wide
}
template <int J>
__device__ __forceinline__ float lx_f(float x) {
  return __builtin_bit_cast(float, lx_i<J>(__builtin_bit_cast(int, x)));
}
__device__ __forceinline__ float rl_f(float v, int l) {
  return __builtin_bit_cast(
      float, __builtin_amdgcn_readlane(__builtin_bit_cast(int, v), l));
}

// Batch merge: 64 per-lane candidates (cd, ci) -> top-16, merged into the
// replicated per-group sorted list (val, vidx). Lexicographic (d, idx).
__device__ __forceinline__ void merge64(float cd, int ci, int sub,
                                        float& val, int& vidx) {
#define CEP(vd, vi, J, KM)                                           \
  {                                                                  \
    float pd_ = lx_f<J>(vd);                                         \
    int pi_ = lx_i<J>(vi);                                           \
    bool ms_ = (vd < pd_) || ((vd == pd_) && (vi < pi_));            \
    bool tm_ = (ms_ == ((((KM) >> sub) & 1) != 0));                  \
    vd = tm_ ? vd : pd_;                                             \
    vi = tm_ ? vi : pi_;                                             \
  }
  // in-group bitonic sort-16 ascending
  CEP(cd, ci, 1, 0x9999u) CEP(cd, ci, 2, 0xC3C3u) CEP(cd, ci, 1, 0xA5A5u)
  CEP(cd, ci, 4, 0xF00Fu) CEP(cd, ci, 2, 0xCC33u) CEP(cd, ci, 1, 0xAA55u)
  CEP(cd, ci, 8, 0x00FFu) CEP(cd, ci, 4, 0x0F0Fu) CEP(cd, ci, 2, 0x3333u)
  CEP(cd, ci, 1, 0x5555u)
  // merge group pairs (0<->1, 2<->3): partner = lane ^ 31 (reversed list)
  {
    float pd = lx_f<31>(cd); int pi = lx_i<31>(ci);
    bool ms = (cd < pd) || ((cd == pd) && (ci < pi));
    cd = ms ? cd : pd; ci = ms ? ci : pi;
  }
  CEP(cd, ci, 8, 0x00FFu) CEP(cd, ci, 4, 0x0F0Fu) CEP(cd, ci, 2, 0x3333u)
  CEP(cd, ci, 1, 0x5555u)
  // merge across pairs: partner = lane ^ 47
  {
    float pd = lx_f<47>(cd); int pi = lx_i<47>(ci);
    bool ms = (cd < pd) || ((cd == pd) && (ci < pi));
    cd = ms ? cd : pd; ci = ms ? ci : pi;
  }
  CEP(cd, ci, 8, 0x00FFu) CEP(cd, ci, 4, 0x0F0Fu) CEP(cd, ci, 2, 0x3333u)
  CEP(cd, ci, 1, 0x5555u)
  // merge candidates-top16 with current list: list reversed in-group (^15)
  {
    float pd = lx_f<15>(val); int pi = lx_i<15>(vidx);
    bool ms = (cd < pd) || ((cd == pd) && (ci < pi));
    val = ms ? cd : pd; vidx = ms ? ci : pi;
  }
  CEP(val, vidx, 8, 0x00FFu) CEP(val, vidx, 4, 0x0F0Fu)
  CEP(val, vidx, 2, 0x3333u) CEP(val, vidx, 1, 0x5555u)
#undef CEP
}

// ---------- knn: one wave per query; 4-chunk seed + frontier traversal ----------
__global__ __launch_bounds__(256) void pw3_knn(
    const float* __restrict__ xyz2, const float4* __restrict__ sp4,
    const float* __restrict__ flow1, const uint* __restrict__ offs,
    const float* __restrict__ lox, const float* __restrict__ hix,
    float* __restrict__ out) {
  int lane = threadIdx.x & 63;
  int sub = lane & 15;
  int wid = (int)((blockIdx.x * 256 + threadIdx.x) >> 6);  // query id
  int b = wid >> 13;
  int n = wid & (N2 - 1);

  const float* x2 = xyz2 + b * 3 * N2;
  float qx = x2[n], qy = x2[N2 + n], qz = x2[2 * N2 + n];
  float n2 = (qx * qx + qy * qy) + qz * qz;

  const float4* __restrict__ src = sp4 + ((size_t)b << 13);

  // per-lane chunk x-bound tables (chunks lane and 64+lane)
  float hx0 = hix[(b << 7) + lane];
  float hx1 = hix[(b << 7) + 64 + lane];
  float lo0 = lox[(b << 7) + lane];
  float lo1 = lox[(b << 7) + 64 + lane];

  int bq = min(max((int)floorf((qx - XMINF) * (1.0f / BWF)), 0), NBUCKET - 1);
  int cs = min((int)(offs[(b << 9) + bq] >> 6), NCHUNKS - 1);
  int cs0 = min(max(cs - 1, 0), NCHUNKS - 4);   // 4 seed chunks cs0..cs0+3

  // ---- seed chunk cs: full-wave bitonic sort-64, lexicographic ----
  float dv; int iv;
  {
    float4 s = src[cs * 64 + lane];
    float nn = fmaf(s.z, s.z, fmaf(s.y, s.y, s.x * s.x));
    float dot = fmaf(s.z, qz, fmaf(s.y, qy, s.x * qx));
    dv = (n2 - 2.0f * dot) + nn;
    iv = __float_as_int(s.w);
  }
#define CE64(K, Jv)                                                  \
  {                                                                  \
    float pd = lx_f<Jv>(dv);                                         \
    int pi = lx_i<Jv>(iv);                                           \
    bool ms = (dv < pd) || ((dv == pd) && (iv < pi));                \
    bool km = ((lane & (K)) == 0) == ((lane & (Jv)) == 0);           \
    bool tm = (ms == km);                                            \
    dv = tm ? dv : pd;                                               \
    iv = tm ? iv : pi;                                               \
  }
  CE64(2, 1)
  CE64(4, 2) CE64(4, 1)
  CE64(8, 4) CE64(8, 2) CE64(8, 1)
  CE64(16, 8) CE64(16, 4) CE64(16, 2) CE64(16, 1)
  CE64(32, 16) CE64(32, 8) CE64(32, 4) CE64(32, 2) CE64(32, 1)
  CE64(64, 32) CE64(64, 16) CE64(64, 8) CE64(64, 4) CE64(64, 2) CE64(64, 1)
#undef CE64

  float val = __shfl(dv, sub);   // replicate top-16 to all four groups
  int vidx = __shfl(iv, sub);

  // ---- remaining 3 seed chunks: unconditional parallel batch merge ----
  #pragma unroll
  for (int j = 0; j < 4; ++j) {
    int cj = cs0 + j;
    if (cj != cs) {
      float4 s = src[cj * 64 + lane];
      float nn = fmaf(s.z, s.z, fmaf(s.y, s.y, s.x * s.x));
      float dot = fmaf(s.z, qz, fmaf(s.y, qy, s.x * qx));
      float dd = (n2 - 2.0f * dot) + nn;
      merge64(dd, __float_as_int(s.w), sub, val, vidx);
    }
  }
  float kth = rl_f(val, 15);

  const float NEG_INF = -INFINITY;
  int lc = cs0 - 1, rc = cs0 + 4;   // frontier starts OUTSIDE seed block

  auto rd128f = [&](float r0, float r1, int c) -> float {
    int a = __builtin_amdgcn_readlane(__builtin_bit_cast(int, r0), c & 63);
    int bb = __builtin_amdgcn_readlane(__builtin_bit_cast(int, r1), c & 63);
    return __builtin_bit_cast(float, (c & 64) ? bb : a);
  };
  auto decide = [&]() -> int {
    float lg = INFINITY, rg = INFINITY;
    if (lc >= 0)       lg = fmaxf(qx - rd128f(hx0, hx1, lc), 0.0f);
    if (rc < NCHUNKS)  rg = fmaxf(rd128f(lo0, lo1, rc) - qx, 0.0f);
    bool left = lg <= rg;
    float g = left ? lg : rg;
    if (!(g * g <= kth + 1e-6f)) return -1;   // INF gap also stops
    int c = left ? lc : rc;
    if (left) --lc; else ++rc;
    return c;
  };

  int c0 = decide();
  float4 s0v;
  if (c0 >= 0) s0v = src[c0 * 64 + lane];
  while (c0 >= 0) {
    int c1 = decide();                 // stale-kth: may over-visit 1 chunk (safe)
    float4 s1v;
    if (c1 >= 0) s1v = src[c1 * 64 + lane];

    int civ = __float_as_int(s0v.w);
    float nn = fmaf(s0v.z, s0v.z, fmaf(s0v.y, s0v.y, s0v.x * s0v.x));
    float dot = fmaf(s0v.z, qz, fmaf(s0v.y, qy, s0v.x * qx));
    float d = (n2 - 2.0f * dot) + nn;

    ull bal = __ballot(d < kth);
    if (bal) {
      int cnt = (int)__popcll(bal);
      if (cnt <= SER_MAX) {
        int dbits = __builtin_bit_cast(int, d);
        do {
          int l = __ffsll(bal) - 1;
          bal &= bal - 1;
          float cd = __builtin_bit_cast(
              float, __builtin_amdgcn_readlane(dbits, l));
          int ci2 = __builtin_amdgcn_readlane(civ, l);
          float pv = dpp_up1_f(val, NEG_INF);
          int pi = dpp_up1_i(vidx);
          bool lt = cd < val;
          bool ltp = cd < pv;
          val = lt ? (ltp ? pv : cd) : val;
          vidx = lt ? (ltp ? pi : ci2) : vidx;
        } while (bal);
      } else {
        merge64(d, civ, sub, val, vidx);
      }
      kth = rl_f(val, 15);
    }
    c0 = c1;
    s0v = s1v;
  }

  // gather selected flows from flow1 and reduce within each 16-lane group
  const float* f1 = flow1 + b * 3 * N1;
  float fx = f1[vidx], fy = f1[N1 + vidx], fz = f1[2 * N1 + vidx];
  #pragma unroll
  for (int o = 8; o > 0; o >>= 1) {
    fx += __shfl_xor(fx, o);
    fy += __shfl_xor(fy, o);
    fz += __shfl_xor(fz, o);
  }

  if (lane == 0) {
    float* op = out + b * 3 * N2;
    const float inv_k = 1.0f / KNN;
    op[n]          = qx - fx * inv_k;
    op[N2 + n]     = qy - fy * inv_k;
    op[2 * N2 + n] = qz - fz * inv_k;
  }
}

extern "C" void kernel_launch(void* const* d_in, const int* in_sizes, int n_in,
                              void* d_out, int out_size, void* d_ws, size_t ws_size,
                              hipStream_t stream) {
  const float* xyz1  = (const float*)d_in[0];
  const float* xyz2  = (const float*)d_in[1];
  const float* flow1 = (const float*)d_in[2];
  float* out = (float*)d_out;

  char* w = (char*)d_ws;
  float4* sp4 = (float4*)w;  w += (size_t)NBATCH * N1 * sizeof(float4);   // 256 KB
  uint* offs  = (uint*)w;    w += NBATCH * NBUCKET * sizeof(uint);        // 4 KB
  float* lox  = (float*)w;   w += NBATCH * NCHUNKS * sizeof(float);       // 1 KB
  float* hix  = (float*)w;   w += NBATCH * NCHUNKS * sizeof(float);       // 1 KB

  pw3_build<<<NBATCH, 1024, 0, stream>>>(xyz1, flow1, sp4, offs, lox, hix);
  pw3_knn<<<(NBATCH * N2 * 64) / 256, 256, 0, stream>>>(xyz2, sp4, flow1, offs,
                                                        lox, hix, out);
}